// Round 1
// baseline (1503.028 us; speedup 1.0000x reference)
//
#include <hip/hip_runtime.h>
#include <math.h>

#define BB 16
#define TT 16
#define KK 4
#define VV 10003
#define DD 256
#define CC 64
#define NTILE 40        // ceil(V/256) v-tiles
#define RPB 16          // rows per k_gemm block
#define VP 10016        // padded row stride for logits scratch
#define FNEG (-1e30f)

typedef float f32x4 __attribute__((ext_vector_type(4)));

// ---------- top-4 list, f32 keys (tie-break: lower index wins) ----------
struct L4 { float v[4]; int ix[4]; };

__device__ __forceinline__ void l4_init(L4 &l) {
#pragma unroll
  for (int j = 0; j < 4; ++j) { l.v[j] = FNEG; l.ix[j] = 0x7fffffff; }
}
__device__ __forceinline__ bool better(float v, int ix, float v2, int ix2) {
  return (v > v2) || (v == v2 && ix < ix2);
}
__device__ __forceinline__ void l4_insert(L4 &l, float v, int ix) {
  if (!better(v, ix, l.v[3], l.ix[3])) return;
  int p = 3;
  while (p > 0 && better(v, ix, l.v[p-1], l.ix[p-1])) {
    l.v[p] = l.v[p-1]; l.ix[p] = l.ix[p-1]; --p;
  }
  l.v[p] = v; l.ix[p] = ix;
}
__device__ __forceinline__ void l4_merge(L4 &a, const L4 &b) {
  L4 r; int ia = 0, ib = 0;
#pragma unroll
  for (int j = 0; j < 4; ++j) {
    if (better(a.v[ia], a.ix[ia], b.v[ib], b.ix[ib])) {
      r.v[j] = a.v[ia]; r.ix[j] = a.ix[ia]; ++ia;
    } else {
      r.v[j] = b.v[ib]; r.ix[j] = b.ix[ib]; ++ib;
    }
  }
  a = r;
}

// ---------- numpy pairwise_sum base case (8 <= n <= 128) — bit-exact ----------
__device__ float np_block_sum(const float* a, int n) {
  float r0=a[0],r1=a[1],r2=a[2],r3=a[3],r4=a[4],r5=a[5],r6=a[6],r7=a[7];
  int i;
  for (i = 8; i + 8 <= n; i += 8) {
    r0 += a[i+0]; r1 += a[i+1]; r2 += a[i+2]; r3 += a[i+3];
    r4 += a[i+4]; r5 += a[i+5]; r6 += a[i+6]; r7 += a[i+7];
  }
  float res = ((r0 + r1) + (r2 + r3)) + ((r4 + r5) + (r6 + r7));
  for (; i < n; ++i) res += a[i];
  return res;
}

// ---------- kernel 0: init chain ----------
__global__ void k_init(const int* __restrict__ loc_tar, int* __restrict__ chainA) {
  int t = threadIdx.x;            // 256 = B*T
  int b = t >> 4, j = t & 15;
  chainA[t] = (j == 0) ? loc_tar[b * TT] : 0;
}

// ---------- kernel 1a: H = E[chain[n,step]] + zs[b]  (wave-uniform operand,
// staged to GLOBAL so k_gemm can read it through the SCALAR pipe) ----------
__global__ __launch_bounds__(256)
void k_h(const float* __restrict__ E, const float* __restrict__ zs,
         const int* __restrict__ chain, float* __restrict__ H,
         int step, int N, int Mshift) {
  int n = blockIdx.x;             // < N
  int d = threadIdx.x;            // 256 = D
  int c = chain[n * TT + step];
  if ((unsigned)c >= VV) c = 0;   // defensive
  int b = n >> Mshift;
  H[n * DD + d] = E[c * DD + d] + zs[b * DD + d];   // same single f32 add as before
}

// ---------- kernel 1b: logits GEMM, scalar-pipe h operand ----------
// Previous version issued one ds_read_b32 per FMA (4096/thread) for the
// wave-uniform xs operand -> per-block LDS latency ~= 40 us regardless of N.
// Now h rows live in GLOBAL (k_h) and are read via batched s_load_dwordx4
// (16 rows x 4 d, single lgkmcnt(0)); FMA consumes the SGPR directly.
// Zero LDS, zero barriers. Arithmetic identical: one f32 acc per (row,col),
// fmaf chain strictly ascending d, bias added after.
__global__ __launch_bounds__(256)
void k_gemm(const float* __restrict__ H, const float* __restrict__ Wv,
            const float* __restrict__ bv, float* __restrict__ Lg, int N) {
  const int t = threadIdx.x;
  const int tile = blockIdx.x % NTILE;        // tile-major => XCD affinity
  const int n0 = (blockIdx.x / NTILE) * RPB;  // N is always a multiple of RPB
  const int v = tile * 256 + t;
  const int vok = (v < VV);
  const int vc = vok ? v : (VV - 1);

  float acc[RPB];
#pragma unroll
  for (int r = 0; r < RPB; ++r) acc[r] = 0.f;

  const float* wq = Wv + vc;                  // per-lane (VGPR) W column ptr
  const float* hp = H + (size_t)n0 * DD;      // wave-uniform (SGPR) h base

  // preload W for chunk 0 (4 d-slices, coalesced b32 each)
  float w0 = wq[0];
  float w1 = wq[(size_t)VV];
  float w2 = wq[(size_t)2 * VV];
  float w3 = wq[(size_t)3 * VV];

  for (int d0 = 0; d0 < DD; d0 += 4) {
    // 16 rows x 4 consecutive d via scalar loads; SMEM may return out of
    // order, so one batched issue + lgkmcnt(0) inside a single asm block.
    // Early-clobber: returns can land before the last load issues.
    f32x4 h[16];
    asm volatile(
      "s_load_dwordx4 %0,  %16, 0x0\n\t"
      "s_load_dwordx4 %1,  %16, 0x400\n\t"
      "s_load_dwordx4 %2,  %16, 0x800\n\t"
      "s_load_dwordx4 %3,  %16, 0xc00\n\t"
      "s_load_dwordx4 %4,  %16, 0x1000\n\t"
      "s_load_dwordx4 %5,  %16, 0x1400\n\t"
      "s_load_dwordx4 %6,  %16, 0x1800\n\t"
      "s_load_dwordx4 %7,  %16, 0x1c00\n\t"
      "s_load_dwordx4 %8,  %16, 0x2000\n\t"
      "s_load_dwordx4 %9,  %16, 0x2400\n\t"
      "s_load_dwordx4 %10, %16, 0x2800\n\t"
      "s_load_dwordx4 %11, %16, 0x2c00\n\t"
      "s_load_dwordx4 %12, %16, 0x3000\n\t"
      "s_load_dwordx4 %13, %16, 0x3400\n\t"
      "s_load_dwordx4 %14, %16, 0x3800\n\t"
      "s_load_dwordx4 %15, %16, 0x3c00\n\t"
      "s_waitcnt lgkmcnt(0)"
      : "=&s"(h[0]),  "=&s"(h[1]),  "=&s"(h[2]),  "=&s"(h[3]),
        "=&s"(h[4]),  "=&s"(h[5]),  "=&s"(h[6]),  "=&s"(h[7]),
        "=&s"(h[8]),  "=&s"(h[9]),  "=&s"(h[10]), "=&s"(h[11]),
        "=&s"(h[12]), "=&s"(h[13]), "=&s"(h[14]), "=&s"(h[15])
      : "s"(hp));

    // prefetch next chunk's W while current FMAs run (clamped ptr: safe
    // in-bounds dummy loads on the final iteration)
    const float* wn = wq + ((d0 + 4 < DD) ? (size_t)4 * VV : (size_t)0);
    float nw0 = wn[0];
    float nw1 = wn[(size_t)VV];
    float nw2 = wn[(size_t)2 * VV];
    float nw3 = wn[(size_t)3 * VV];

#pragma unroll
    for (int r = 0; r < RPB; ++r) {
      float a = acc[r];
      a = fmaf(h[r][0], w0, a);      // d ascending, one acc per output
      a = fmaf(h[r][1], w1, a);
      a = fmaf(h[r][2], w2, a);
      a = fmaf(h[r][3], w3, a);
      acc[r] = a;
    }

    w0 = nw0; w1 = nw1; w2 = nw2; w3 = nw3;
    wq += (size_t)4 * VV;
    hp += 4;
  }

  if (vok) {
    const float bvv = bv[v];
#pragma unroll
    for (int r = 0; r < RPB; ++r)
      Lg[(size_t)(n0 + r) * VP + v] = acc[r] + bvv;   // bias after gemm (np)
  }
}

// ---------- kernel 2: np-exact max/top4/pairwise-lse, 1024-thread ----------
// Same math as before (max / top4 under a strict total order are
// partition-independent; leaf segments + pairwise tree unchanged; double
// exp/log unchanged). 4x more threads, row values kept in registers through
// the scan (single LDS write of the exp'd value), shfl-based reductions.
__global__ __launch_bounds__(1024)
void k_red(const float* __restrict__ Lg, float* __restrict__ topP,
           int* __restrict__ topI) {
  __shared__ float row[VV];          // exp'd values (for the pairwise sums)
  __shared__ int   segBase[255];
  __shared__ int   segN[255];
  __shared__ float val[255];
  __shared__ float wmax[16];
  __shared__ float wv4[16 * 4];
  __shared__ int   wi4[16 * 4];
  __shared__ float gmS;
  __shared__ float gtv[4];
  __shared__ int   gti[4];

  const int n = blockIdx.x;
  const int t = threadIdx.x;
  const int lane = t & 63;
  const int wid = t >> 6;
  const float* grow = Lg + (size_t)n * VP;

  // load + scan in registers (each thread owns v = t + 1024k)
  float xr[10];
  float m = FNEG;
  L4 top; l4_init(top);
#pragma unroll
  for (int k = 0; k < 10; ++k) {
    int v = t + (k << 10);
    if (v < VV) {
      float x = grow[v];
      xr[k] = x;
      if (x > m) m = x;
      l4_insert(top, x, v);
    }
  }

  // intra-wave reduce (64 lanes, butterfly)
  for (int off = 32; off; off >>= 1) {
    float m2 = __shfl_xor(m, off);
    if (m2 > m) m = m2;
    L4 o;
#pragma unroll
    for (int j = 0; j < 4; ++j) {
      o.v[j]  = __shfl_xor(top.v[j], off);
      o.ix[j] = __shfl_xor(top.ix[j], off);
    }
    l4_merge(top, o);
  }
  if (lane == 0) {
    wmax[wid] = m;
#pragma unroll
    for (int j = 0; j < 4; ++j) { wv4[wid * 4 + j] = top.v[j]; wi4[wid * 4 + j] = top.ix[j]; }
  }
  if (t == 0) { segBase[0] = 0; segN[0] = VV; }
  __syncthreads();

  // cross-wave merge of the 16 partials (lanes 0..15 of wave 0)
  if (t < 16) {
    float mm = wmax[t];
    L4 a;
#pragma unroll
    for (int j = 0; j < 4; ++j) { a.v[j] = wv4[t * 4 + j]; a.ix[j] = wi4[t * 4 + j]; }
    for (int off = 1; off < 16; off <<= 1) {
      float m2 = __shfl_xor(mm, off);
      if (m2 > mm) mm = m2;
      L4 o;
#pragma unroll
      for (int j = 0; j < 4; ++j) {
        o.v[j]  = __shfl_xor(a.v[j], off);
        o.ix[j] = __shfl_xor(a.ix[j], off);
      }
      l4_merge(a, o);
    }
    if (t == 0) {
      gmS = mm;
#pragma unroll
      for (int j = 0; j < 4; ++j) { gtv[j] = a.v[j]; gti[j] = a.ix[j]; }
    }
  }

  // numpy pairwise segment tree (structure unchanged)
  for (int L = 0; L < 7; ++L) {
    int first = (1 << L) - 1, cnt = 1 << L;
    if (t < cnt) {
      int p = first + t;
      int np_ = segN[p], bp = segBase[p];
      int n2 = np_ / 2; n2 -= n2 % 8;
      segBase[2 * p + 1] = bp;       segN[2 * p + 1] = n2;
      segBase[2 * p + 2] = bp + n2;  segN[2 * p + 2] = np_ - n2;
    }
    __syncthreads();
  }
  const float gm = gmS;   // visible: t==0 wrote it before the tree barriers

  // exp pass: f32 sub, double exp, store f32 (identical to before)
#pragma unroll
  for (int k = 0; k < 10; ++k) {
    int v = t + (k << 10);
    if (v < VV) row[v] = (float)exp((double)(xr[k] - gm));
  }
  __syncthreads();

  if (t < 128) {
    int nd = 127 + t;
    val[nd] = np_block_sum(&row[segBase[nd]], segN[nd]);
  }
  for (int L = 6; L >= 0; --L) {
    __syncthreads();
    int first = (1 << L) - 1, cnt = 1 << L;
    if (t < cnt) {
      int p = first + t;
      val[p] = val[2 * p + 1] + val[2 * p + 2];
    }
  }

  if (t == 0) {
    float ls = (float)log((double)val[0]);
#pragma unroll
    for (int j = 0; j < 4; ++j) {
      topP[n * 4 + j] = (gtv[j] - gm) - ls;   // (x - m) - log(s), two f32 subs
      topI[n * 4 + j] = gti[j];
    }
  }
}

// ---------- kernel 3: beam update, wave-parallel (UNCHANGED) ----------
__global__ __launch_bounds__(512)
void k_beam(const float* __restrict__ topP, const int* __restrict__ topI,
            float* __restrict__ prob, const int* __restrict__ chain_cur,
            int* __restrict__ chain_next, int step) {
  __shared__ int sel_src[BB][8];
  __shared__ int sel_tok[BB][8];

  const int tid = threadIdx.x;
  const int b = tid >> 5;      // batch 0..15
  const int c = tid & 31;      // candidate 0..31

  if (step == 0) {
    for (int e = tid; e < BB * KK * TT; e += 512) {
      int dst = e >> 4, q = e & 15;
      int bb = dst >> 2, kk = dst & 3;
      int val;
      if (q == 1) {
        int tok = topI[bb * 4 + kk]; if ((unsigned)tok >= VV) tok = 0;
        val = tok;
      } else {
        val = chain_cur[bb * TT + q];
      }
      chain_next[dst * TT + q] = val;
    }
    if (tid < BB * KK) {
      int bb = tid >> 2, kk = tid & 3;
      prob[bb * 8 + kk] = topP[bb * 4 + kk];
    }
    return;
  }

  const int M = (step == 1) ? 4 : 8;
  const int nc = M * 4;

  float act;
  if (c < nc) {
    int m = c >> 2, k = c & 3;
    act = prob[b * 8 + m] * topP[(b * M + m) * 4 + k];
  } else {
    act = -INFINITY;
  }

  for (int j = 0; j < 8; ++j) {
    float rv = act; int ri = c;
#pragma unroll
    for (int off = 1; off < 32; off <<= 1) {
      float v2 = __shfl_xor(rv, off, 32);
      int   i2 = __shfl_xor(ri, off, 32);
      if (v2 > rv || (v2 == rv && i2 < ri)) { rv = v2; ri = i2; }
    }
    if (c == ri) act = -INFINITY;          // mark used
    if (c == 0) {
      int m = ri >> 2, k = ri & 3;
      int src = b * M + m;
      int tok = topI[src * 4 + k]; if ((unsigned)tok >= VV) tok = 0;
      sel_src[b][j] = src;
      sel_tok[b][j] = tok;
      prob[b * 8 + j] = rv;
    }
  }
  __syncthreads();

  for (int e = tid; e < BB * 8 * TT; e += 512) {
    int dst = e >> 4, q = e & 15;
    int bb = dst >> 3, j = dst & 7;
    int src = sel_src[bb][j];
    int val = (q == step + 1) ? sel_tok[bb][j] : chain_cur[src * TT + q];
    chain_next[dst * TT + q] = val;
  }
}

// ---------- kernel 4: finalize: loc_chain + tim_chain (UNCHANGED) ----------
__global__ __launch_bounds__(64)
void k_final(const int* __restrict__ chain, const float* __restrict__ E,
             const float* __restrict__ Wc, const float* __restrict__ bc,
             const float* __restrict__ Wt, const float* __restrict__ zt,
             const float* __restrict__ Wzt, float* __restrict__ out) {
  int blk = blockIdx.x;           // 224 = B*(T-2)
  int b = blk / (TT - 2), t = blk % (TT - 2);
  int lane = threadIdx.x;         // 64 = C
  int loc = chain[(b * 8) * TT + 1 + t];   // best beam, positions 1..T-2
  if ((unsigned)loc >= VV) loc = 0;        // defensive
  double acc = (double)bc[lane];
  const float* er = E + loc * DD;
  for (int d = 0; d < DD; ++d) acc += (double)er[d] * (double)Wc[d * CC + lane];
  double val = tanh(acc) * (double)Wt[lane];
  const float* ztr = zt + b * DD;
#pragma unroll
  for (int q = 0; q < 4; ++q) val += (double)ztr[lane * 4 + q] * (double)Wzt[lane * 4 + q];
  for (int off = 32; off; off >>= 1) val += __shfl_down(val, off);
  if (lane == 0) {
    out[b * (TT - 2) + t] = (float)loc;                 // loc_chain as float
    out[BB * (TT - 2) + b * (TT - 2) + t] = (float)val; // tim_chain
  }
}

// ---------- host ----------
extern "C" void kernel_launch(void* const* d_in, const int* in_sizes, int n_in,
                              void* d_out, int out_size, void* d_ws, size_t ws_size,
                              hipStream_t stream) {
  const int*   loc_tar = (const int*)  d_in[0];
  const float* zs      = (const float*)d_in[1];
  const float* zt      = (const float*)d_in[2];
  const float* E       = (const float*)d_in[3];
  const float* Wv      = (const float*)d_in[4];
  const float* bv      = (const float*)d_in[5];
  const float* Wc      = (const float*)d_in[6];
  const float* bc      = (const float*)d_in[7];
  const float* Wt      = (const float*)d_in[8];
  const float* Wzt     = (const float*)d_in[9];
  float* out = (float*)d_out;

  char* w = (char*)d_ws;
  float* Lg     = (float*)(w);                   // 128*10016*4 = 5,128,192 B
  float* topP   = (float*)(w + 5128192);         // 512 f32 = 2048 B
  int*   topI   = (int*)  (w + 5130240);         // 512 int = 2048 B
  float* prob   = (float*)(w + 5132288);         // 128 f32 = 512 B
  int*   chainA = (int*)  (w + 5132800);         // 2048 int = 8192 B
  int*   chainB = (int*)  (w + 5140992);         // 2048 int = 8192 B
  float* H      = (float*)(w + 5149184);         // 128*256 f32 = 131072 B

  k_init<<<1, 256, 0, stream>>>(loc_tar, chainA);

  int N = BB;
  int* cur = chainA;
  int* nxt = chainB;
  for (int i = 0; i < TT - 1; ++i) {
    int Mshift = (i == 0) ? 0 : ((i == 1) ? 2 : 3);
    k_h<<<N, 256, 0, stream>>>(E, zs, cur, H, i, N, Mshift);
    int ntn = N / RPB;
    k_gemm<<<ntn * NTILE, 256, 0, stream>>>(H, Wv, bv, Lg, N);
    k_red<<<N, 1024, 0, stream>>>(Lg, topP, topI);
    k_beam<<<1, 512, 0, stream>>>(topP, topI, prob, cur, nxt, i);
    int* t2 = cur; cur = nxt; nxt = t2;
    N = (i == 0) ? BB * KK : BB * 2 * KK;
  }

  k_final<<<BB * (TT - 2), 64, 0, stream>>>(cur, E, Wc, bc, Wt, zt, Wzt, out);
}

// Round 2
// 1280.922 us; speedup vs baseline: 1.1734x; 1.1734x over previous
//
#include <hip/hip_runtime.h>
#include <math.h>

#define BB 16
#define TT 16
#define KK 4
#define VV 10003
#define DD 256
#define CC 64
#define RPB 4           // rows per k_gemm block
#define VPT 5           // v-columns per thread
#define VT  1280        // v-span per block = 256*VPT
#define NVT 8           // v-tiles = ceil(10003/1280); 8 tiles -> tile==XCD (stable)
#define VP 10016        // padded row stride for logits scratch
#define FNEG (-1e30f)

typedef float f32x4 __attribute__((ext_vector_type(4)));

// ---------- top-4 list, f32 keys (tie-break: lower index wins) ----------
struct L4 { float v[4]; int ix[4]; };

__device__ __forceinline__ void l4_init(L4 &l) {
#pragma unroll
  for (int j = 0; j < 4; ++j) { l.v[j] = FNEG; l.ix[j] = 0x7fffffff; }
}
__device__ __forceinline__ bool better(float v, int ix, float v2, int ix2) {
  return (v > v2) || (v == v2 && ix < ix2);
}
__device__ __forceinline__ void l4_insert(L4 &l, float v, int ix) {
  if (!better(v, ix, l.v[3], l.ix[3])) return;
  int p = 3;
  while (p > 0 && better(v, ix, l.v[p-1], l.ix[p-1])) {
    l.v[p] = l.v[p-1]; l.ix[p] = l.ix[p-1]; --p;
  }
  l.v[p] = v; l.ix[p] = ix;
}
__device__ __forceinline__ void l4_merge(L4 &a, const L4 &b) {
  L4 r; int ia = 0, ib = 0;
#pragma unroll
  for (int j = 0; j < 4; ++j) {
    if (better(a.v[ia], a.ix[ia], b.v[ib], b.ix[ib])) {
      r.v[j] = a.v[ia]; r.ix[j] = a.ix[ia]; ++ia;
    } else {
      r.v[j] = b.v[ib]; r.ix[j] = b.ix[ib]; ++ib;
    }
  }
  a = r;
}

// ---------- numpy pairwise_sum base case (8 <= n <= 128) — bit-exact ----------
__device__ float np_block_sum(const float* a, int n) {
  float r0=a[0],r1=a[1],r2=a[2],r3=a[3],r4=a[4],r5=a[5],r6=a[6],r7=a[7];
  int i;
  for (i = 8; i + 8 <= n; i += 8) {
    r0 += a[i+0]; r1 += a[i+1]; r2 += a[i+2]; r3 += a[i+3];
    r4 += a[i+4]; r5 += a[i+5]; r6 += a[i+6]; r7 += a[i+7];
  }
  float res = ((r0 + r1) + (r2 + r3)) + ((r4 + r5) + (r6 + r7));
  for (; i < n; ++i) res += a[i];
  return res;
}

// ---------- kernel 0: init chain ----------
__global__ void k_init(const int* __restrict__ loc_tar, int* __restrict__ chainA) {
  int t = threadIdx.x;            // 256 = B*T
  int b = t >> 4, j = t & 15;
  chainA[t] = (j == 0) ? loc_tar[b * TT] : 0;
}

// ---------- kernel 1: logits GEMM, b128 LDS + 5-col register reuse ----------
// Round-0 version was LDS-pipe bound: 4096 wave-uniform ds_read_b32 per wave
// (one per FMA) -> ~95k cyc/CU ~= 40 us. Now each h chunk is read once as
// ds_read_b128 and feeds VPT=5 columns: per-wave LDS = 256 b128 (16x fewer
// instructions, ~8x fewer LDS cycles). 8 v-tiles of 1280 -> tile == bid%8 ==
// XCD (round-robin dispatch), so each XCD's 1.28 MB Wv slice is L2-resident
// across row-groups and steps; grid at N=128 is exactly 256 blocks (1/CU).
// Arithmetic identical to the 1331us baseline: h = E[c]+zs[b] (one f32 add),
// one f32 acc per (row,col), fmaf strictly ascending d, bias added after.
__global__ __launch_bounds__(256)
void k_gemm(const float* __restrict__ E, const float* __restrict__ zs,
            const float* __restrict__ Wv, const float* __restrict__ bv,
            const int* __restrict__ chain, float* __restrict__ Lg,
            int step, int N, int Mshift) {
  __shared__ float xs[RPB * DD];     // 4 KB (h rows, broadcast-read)
  __shared__ int cs[RPB];

  const int t = threadIdx.x;
  const int tile = blockIdx.x % NVT;          // tile == XCD (stable mapping)
  const int n0 = (blockIdx.x / NVT) * RPB;    // N is a multiple of RPB
  const int v0 = tile * VT;

  int vcol[VPT]; int vok[VPT];
#pragma unroll
  for (int c = 0; c < VPT; ++c) {
    int v = v0 + (c << 8) + t;
    vok[c] = (v < VV);
    vcol[c] = vok[c] ? v : (VV - 1);
  }

  if (t < RPB) {
    int n = n0 + t;
    int c = chain[n * TT + step];
    if ((unsigned)c >= VV) c = 0;    // defensive
    cs[t] = c;
  }
  __syncthreads();

  // stage xs rows: h = E[c] + zs[b]  (single f32 add, np order)
  for (int e = t; e < RPB * DD; e += 256) {
    int r = e >> 8, d = e & 255;
    int n = n0 + r;
    int b = n >> Mshift;
    xs[e] = E[cs[r] * DD + d] + zs[b * DD + d];
  }
  __syncthreads();

  const float* wp[VPT];
#pragma unroll
  for (int c = 0; c < VPT; ++c) wp[c] = Wv + vcol[c];

  float acc[RPB][VPT];
#pragma unroll
  for (int r = 0; r < RPB; ++r)
#pragma unroll
    for (int c = 0; c < VPT; ++c) acc[r][c] = 0.f;

  // ping-pong double buffer: set A / set B, chunk = 4 d
  f32x4 hA[RPB], hB[RPB];
  float wA[VPT][4], wB[VPT][4];

#pragma unroll
  for (int r = 0; r < RPB; ++r) hA[r] = *(const f32x4*)(xs + r * DD);
#pragma unroll
  for (int c = 0; c < VPT; ++c)
#pragma unroll
    for (int u = 0; u < 4; ++u) wA[c][u] = wp[c][(size_t)u * VV];

  for (int d0 = 0; d0 < DD; d0 += 8) {
    const int dB = d0 + 4;
    // prefetch set B (chunk dB) while computing with A
#pragma unroll
    for (int r = 0; r < RPB; ++r) hB[r] = *(const f32x4*)(xs + r * DD + dB);
#pragma unroll
    for (int c = 0; c < VPT; ++c)
#pragma unroll
      for (int u = 0; u < 4; ++u) wB[c][u] = wp[c][(size_t)(dB + u) * VV];

#pragma unroll
    for (int r = 0; r < RPB; ++r)
#pragma unroll
      for (int c = 0; c < VPT; ++c) {
        float a = acc[r][c];
        a = fmaf(hA[r][0], wA[c][0], a);   // d ascending, one acc per output
        a = fmaf(hA[r][1], wA[c][1], a);
        a = fmaf(hA[r][2], wA[c][2], a);
        a = fmaf(hA[r][3], wA[c][3], a);
        acc[r][c] = a;
      }

    const int dA = (d0 + 8 < DD) ? (d0 + 8) : 0;   // dummy reload on last iter
    // prefetch set A (chunk dA) while computing with B
#pragma unroll
    for (int r = 0; r < RPB; ++r) hA[r] = *(const f32x4*)(xs + r * DD + dA);
#pragma unroll
    for (int c = 0; c < VPT; ++c)
#pragma unroll
      for (int u = 0; u < 4; ++u) wA[c][u] = wp[c][(size_t)(dA + u) * VV];

#pragma unroll
    for (int r = 0; r < RPB; ++r)
#pragma unroll
      for (int c = 0; c < VPT; ++c) {
        float a = acc[r][c];
        a = fmaf(hB[r][0], wB[c][0], a);
        a = fmaf(hB[r][1], wB[c][1], a);
        a = fmaf(hB[r][2], wB[c][2], a);
        a = fmaf(hB[r][3], wB[c][3], a);
        acc[r][c] = a;
      }
  }

#pragma unroll
  for (int c = 0; c < VPT; ++c) {
    if (vok[c]) {
      const int v = vcol[c];
      const float bvv = bv[v];
#pragma unroll
      for (int r = 0; r < RPB; ++r)
        Lg[(size_t)(n0 + r) * VP + v] = acc[r][c] + bvv;  // bias after gemm (np)
    }
  }
}

// ---------- kernel 2: np-exact max/top4/pairwise-lse, 1024-thread ----------
__global__ __launch_bounds__(1024)
void k_red(const float* __restrict__ Lg, float* __restrict__ topP,
           int* __restrict__ topI) {
  __shared__ float row[VV];          // exp'd values (for the pairwise sums)
  __shared__ int   segBase[255];
  __shared__ int   segN[255];
  __shared__ float val[255];
  __shared__ float wmax[16];
  __shared__ float wv4[16 * 4];
  __shared__ int   wi4[16 * 4];
  __shared__ float gmS;
  __shared__ float gtv[4];
  __shared__ int   gti[4];

  const int n = blockIdx.x;
  const int t = threadIdx.x;
  const int lane = t & 63;
  const int wid = t >> 6;
  const float* grow = Lg + (size_t)n * VP;

  // load + scan in registers (each thread owns v = t + 1024k)
  float xr[10];
  float m = FNEG;
  L4 top; l4_init(top);
#pragma unroll
  for (int k = 0; k < 10; ++k) {
    int v = t + (k << 10);
    if (v < VV) {
      float x = grow[v];
      xr[k] = x;
      if (x > m) m = x;
      l4_insert(top, x, v);
    }
  }

  // intra-wave reduce (64 lanes, butterfly)
  for (int off = 32; off; off >>= 1) {
    float m2 = __shfl_xor(m, off);
    if (m2 > m) m = m2;
    L4 o;
#pragma unroll
    for (int j = 0; j < 4; ++j) {
      o.v[j]  = __shfl_xor(top.v[j], off);
      o.ix[j] = __shfl_xor(top.ix[j], off);
    }
    l4_merge(top, o);
  }
  if (lane == 0) {
    wmax[wid] = m;
#pragma unroll
    for (int j = 0; j < 4; ++j) { wv4[wid * 4 + j] = top.v[j]; wi4[wid * 4 + j] = top.ix[j]; }
  }
  if (t == 0) { segBase[0] = 0; segN[0] = VV; }
  __syncthreads();

  // cross-wave merge of the 16 partials (lanes 0..15 of wave 0)
  if (t < 16) {
    float mm = wmax[t];
    L4 a;
#pragma unroll
    for (int j = 0; j < 4; ++j) { a.v[j] = wv4[t * 4 + j]; a.ix[j] = wi4[t * 4 + j]; }
    for (int off = 1; off < 16; off <<= 1) {
      float m2 = __shfl_xor(mm, off);
      if (m2 > mm) mm = m2;
      L4 o;
#pragma unroll
      for (int j = 0; j < 4; ++j) {
        o.v[j]  = __shfl_xor(a.v[j], off);
        o.ix[j] = __shfl_xor(a.ix[j], off);
      }
      l4_merge(a, o);
    }
    if (t == 0) {
      gmS = mm;
#pragma unroll
      for (int j = 0; j < 4; ++j) { gtv[j] = a.v[j]; gti[j] = a.ix[j]; }
    }
  }

  // numpy pairwise segment tree (structure unchanged)
  for (int L = 0; L < 7; ++L) {
    int first = (1 << L) - 1, cnt = 1 << L;
    if (t < cnt) {
      int p = first + t;
      int np_ = segN[p], bp = segBase[p];
      int n2 = np_ / 2; n2 -= n2 % 8;
      segBase[2 * p + 1] = bp;       segN[2 * p + 1] = n2;
      segBase[2 * p + 2] = bp + n2;  segN[2 * p + 2] = np_ - n2;
    }
    __syncthreads();
  }
  const float gm = gmS;   // visible: t==0 wrote it before the tree barriers

  // exp pass: f32 sub, double exp, store f32 (identical to before)
#pragma unroll
  for (int k = 0; k < 10; ++k) {
    int v = t + (k << 10);
    if (v < VV) row[v] = (float)exp((double)(xr[k] - gm));
  }
  __syncthreads();

  if (t < 128) {
    int nd = 127 + t;
    val[nd] = np_block_sum(&row[segBase[nd]], segN[nd]);
  }
  for (int L = 6; L >= 0; --L) {
    __syncthreads();
    int first = (1 << L) - 1, cnt = 1 << L;
    if (t < cnt) {
      int p = first + t;
      val[p] = val[2 * p + 1] + val[2 * p + 2];
    }
  }

  if (t == 0) {
    float ls = (float)log((double)val[0]);
#pragma unroll
    for (int j = 0; j < 4; ++j) {
      topP[n * 4 + j] = (gtv[j] - gm) - ls;   // (x - m) - log(s), two f32 subs
      topI[n * 4 + j] = gti[j];
    }
  }
}

// ---------- kernel 3: beam update, wave-parallel (UNCHANGED) ----------
__global__ __launch_bounds__(512)
void k_beam(const float* __restrict__ topP, const int* __restrict__ topI,
            float* __restrict__ prob, const int* __restrict__ chain_cur,
            int* __restrict__ chain_next, int step) {
  __shared__ int sel_src[BB][8];
  __shared__ int sel_tok[BB][8];

  const int tid = threadIdx.x;
  const int b = tid >> 5;      // batch 0..15
  const int c = tid & 31;      // candidate 0..31

  if (step == 0) {
    for (int e = tid; e < BB * KK * TT; e += 512) {
      int dst = e >> 4, q = e & 15;
      int bb = dst >> 2, kk = dst & 3;
      int val;
      if (q == 1) {
        int tok = topI[bb * 4 + kk]; if ((unsigned)tok >= VV) tok = 0;
        val = tok;
      } else {
        val = chain_cur[bb * TT + q];
      }
      chain_next[dst * TT + q] = val;
    }
    if (tid < BB * KK) {
      int bb = tid >> 2, kk = tid & 3;
      prob[bb * 8 + kk] = topP[bb * 4 + kk];
    }
    return;
  }

  const int M = (step == 1) ? 4 : 8;
  const int nc = M * 4;

  float act;
  if (c < nc) {
    int m = c >> 2, k = c & 3;
    act = prob[b * 8 + m] * topP[(b * M + m) * 4 + k];
  } else {
    act = -INFINITY;
  }

  for (int j = 0; j < 8; ++j) {
    float rv = act; int ri = c;
#pragma unroll
    for (int off = 1; off < 32; off <<= 1) {
      float v2 = __shfl_xor(rv, off, 32);
      int   i2 = __shfl_xor(ri, off, 32);
      if (v2 > rv || (v2 == rv && i2 < ri)) { rv = v2; ri = i2; }
    }
    if (c == ri) act = -INFINITY;          // mark used
    if (c == 0) {
      int m = ri >> 2, k = ri & 3;
      int src = b * M + m;
      int tok = topI[src * 4 + k]; if ((unsigned)tok >= VV) tok = 0;
      sel_src[b][j] = src;
      sel_tok[b][j] = tok;
      prob[b * 8 + j] = rv;
    }
  }
  __syncthreads();

  for (int e = tid; e < BB * 8 * TT; e += 512) {
    int dst = e >> 4, q = e & 15;
    int bb = dst >> 3, j = dst & 7;
    int src = sel_src[bb][j];
    int val = (q == step + 1) ? sel_tok[bb][j] : chain_cur[src * TT + q];
    chain_next[dst * TT + q] = val;
  }
}

// ---------- kernel 4: finalize: loc_chain + tim_chain (UNCHANGED) ----------
__global__ __launch_bounds__(64)
void k_final(const int* __restrict__ chain, const float* __restrict__ E,
             const float* __restrict__ Wc, const float* __restrict__ bc,
             const float* __restrict__ Wt, const float* __restrict__ zt,
             const float* __restrict__ Wzt, float* __restrict__ out) {
  int blk = blockIdx.x;           // 224 = B*(T-2)
  int b = blk / (TT - 2), t = blk % (TT - 2);
  int lane = threadIdx.x;         // 64 = C
  int loc = chain[(b * 8) * TT + 1 + t];   // best beam, positions 1..T-2
  if ((unsigned)loc >= VV) loc = 0;        // defensive
  double acc = (double)bc[lane];
  const float* er = E + loc * DD;
  for (int d = 0; d < DD; ++d) acc += (double)er[d] * (double)Wc[d * CC + lane];
  double val = tanh(acc) * (double)Wt[lane];
  const float* ztr = zt + b * DD;
#pragma unroll
  for (int q = 0; q < 4; ++q) val += (double)ztr[lane * 4 + q] * (double)Wzt[lane * 4 + q];
  for (int off = 32; off; off >>= 1) val += __shfl_down(val, off);
  if (lane == 0) {
    out[b * (TT - 2) + t] = (float)loc;                 // loc_chain as float
    out[BB * (TT - 2) + b * (TT - 2) + t] = (float)val; // tim_chain
  }
}

// ---------- host ----------
extern "C" void kernel_launch(void* const* d_in, const int* in_sizes, int n_in,
                              void* d_out, int out_size, void* d_ws, size_t ws_size,
                              hipStream_t stream) {
  const int*   loc_tar = (const int*)  d_in[0];
  const float* zs      = (const float*)d_in[1];
  const float* zt      = (const float*)d_in[2];
  const float* E       = (const float*)d_in[3];
  const float* Wv      = (const float*)d_in[4];
  const float* bv      = (const float*)d_in[5];
  const float* Wc      = (const float*)d_in[6];
  const float* bc      = (const float*)d_in[7];
  const float* Wt      = (const float*)d_in[8];
  const float* Wzt     = (const float*)d_in[9];
  float* out = (float*)d_out;

  char* w = (char*)d_ws;
  float* Lg     = (float*)(w);                   // 128*10016*4 = 5,128,192 B
  float* topP   = (float*)(w + 5128192);         // 512 f32 = 2048 B
  int*   topI   = (int*)  (w + 5130240);         // 512 int = 2048 B
  float* prob   = (float*)(w + 5132288);         // 128 f32 = 512 B
  int*   chainA = (int*)  (w + 5132800);         // 2048 int = 8192 B
  int*   chainB = (int*)  (w + 5140992);         // 2048 int = 8192 B

  k_init<<<1, 256, 0, stream>>>(loc_tar, chainA);

  int N = BB;
  int* cur = chainA;
  int* nxt = chainB;
  for (int i = 0; i < TT - 1; ++i) {
    int Mshift = (i == 0) ? 0 : ((i == 1) ? 2 : 3);
    int nrg = N / RPB;
    k_gemm<<<nrg * NVT, 256, 0, stream>>>(E, zs, Wv, bv, cur, Lg, i, N, Mshift);
    k_red<<<N, 1024, 0, stream>>>(Lg, topP, topI);
    k_beam<<<1, 512, 0, stream>>>(topP, topI, prob, cur, nxt, i);
    int* t2 = cur; cur = nxt; nxt = t2;
    N = (i == 0) ? BB * KK : BB * 2 * KK;
  }

  k_final<<<BB * (TT - 2), 64, 0, stream>>>(cur, E, Wc, bc, Wt, zt, Wzt, out);
}

// Round 3
// 1042.690 us; speedup vs baseline: 1.4415x; 1.2285x over previous
//
#include <hip/hip_runtime.h>
#include <math.h>

#define BB 16
#define TT 16
#define KK 4
#define VV 10003
#define DD 256
#define CC 64
#define RPB 4           // rows per k_gemm block
#define VT  1280        // v-span per block: 1024 (4/thread packed) + 256 (1/thread)
#define NVT 8           // v-tiles; 8 tiles -> tile == bid%8 == XCD (stable)
#define VP 10016        // padded row stride for logits scratch
#define FNEG (-1e30f)

typedef float f32x4 __attribute__((ext_vector_type(4)));
// 4-float vector with only 4-byte alignment guaranteed (Wv row stride 10003
// floats is odd, so d-slices of a column group are not 16B-aligned)
typedef float f32x4u __attribute__((ext_vector_type(4), aligned(4)));

// ---------- top-4, branch-free named-scalar version ----------
// Previous version runtime-indexed l.v[p] / a.v[ia] -> compiler placed the
// whole L4 state in SCRATCH (k_red showed VGPR_Count=20 with ~1 MB of
// FETCH+WRITE per dispatch, 50 us/block). Named scalars + select network
// keep everything in VGPRs. List kept sorted (descending) under the strict
// total order (v desc, index asc tie-break), so better(x,e0) implies
// better(x,e1) etc., and the 4-level conditional shift below is exact.
struct L4 { float v0, v1, v2, v3; int i0, i1, i2, i3; };

__device__ __forceinline__ void l4_init(L4 &l) {
  l.v0 = l.v1 = l.v2 = l.v3 = FNEG;
  l.i0 = l.i1 = l.i2 = l.i3 = 0x7fffffff;
}
__device__ __forceinline__ bool better(float v, int ix, float v2, int ix2) {
  return (v > v2) || (v == v2 && ix < ix2);
}
__device__ __forceinline__ void l4_insert(L4 &l, float v, int ix) {
  const bool c0 = better(v, ix, l.v0, l.i0);
  const bool c1 = better(v, ix, l.v1, l.i1);
  const bool c2 = better(v, ix, l.v2, l.i2);
  const bool c3 = better(v, ix, l.v3, l.i3);
  // update back-to-front with OLD values (sorted => c0=>c1=>c2=>c3)
  l.v3 = c3 ? (c2 ? l.v2 : v) : l.v3;  l.i3 = c3 ? (c2 ? l.i2 : ix) : l.i3;
  l.v2 = c2 ? (c1 ? l.v1 : v) : l.v2;  l.i2 = c2 ? (c1 ? l.i1 : ix) : l.i2;
  l.v1 = c1 ? (c0 ? l.v0 : v) : l.v1;  l.i1 = c1 ? (c0 ? l.i0 : ix) : l.i1;
  l.v0 = c0 ? v : l.v0;                l.i0 = c0 ? ix : l.i0;
}
__device__ __forceinline__ void l4_merge(L4 &a, const L4 &b) {
  // top-4 of a union b == insert b's elements (total order => well-defined)
  l4_insert(a, b.v0, b.i0);
  l4_insert(a, b.v1, b.i1);
  l4_insert(a, b.v2, b.i2);
  l4_insert(a, b.v3, b.i3);
}
__device__ __forceinline__ L4 l4_shfl_xor(const L4 &a, int off) {
  L4 o;
  o.v0 = __shfl_xor(a.v0, off); o.i0 = __shfl_xor(a.i0, off);
  o.v1 = __shfl_xor(a.v1, off); o.i1 = __shfl_xor(a.i1, off);
  o.v2 = __shfl_xor(a.v2, off); o.i2 = __shfl_xor(a.i2, off);
  o.v3 = __shfl_xor(a.v3, off); o.i3 = __shfl_xor(a.i3, off);
  return o;
}

// ---------- numpy pairwise_sum base case (8 <= n <= 128) — bit-exact ----------
__device__ float np_block_sum(const float* a, int n) {
  float r0=a[0],r1=a[1],r2=a[2],r3=a[3],r4=a[4],r5=a[5],r6=a[6],r7=a[7];
  int i;
  for (i = 8; i + 8 <= n; i += 8) {
    r0 += a[i+0]; r1 += a[i+1]; r2 += a[i+2]; r3 += a[i+3];
    r4 += a[i+4]; r5 += a[i+5]; r6 += a[i+6]; r7 += a[i+7];
  }
  float res = ((r0 + r1) + (r2 + r3)) + ((r4 + r5) + (r6 + r7));
  for (; i < n; ++i) res += a[i];
  return res;
}

// ---------- kernel 0: init chain ----------
__global__ void k_init(const int* __restrict__ loc_tar, int* __restrict__ chainA) {
  int t = threadIdx.x;            // 256 = B*T
  int b = t >> 4, j = t & 15;
  chainA[t] = (j == 0) ? loc_tar[b * TT] : 0;
}

// ---------- kernel 1: logits GEMM, x4 W loads + 8-d double buffer ----------
// Each thread owns 4 CONSECUTIVE v columns (one dwordx4 W load per d) plus
// one extra column (b32): 16 VMEM per 8-d group vs 40 with all-scalar loads.
// 8 tiles of 1280 -> tile == bid%8 == XCD (round-robin dispatch), Wv slice
// L2-resident across row-groups/steps. Grid at N=128: 256 blocks = 1/CU.
// Arithmetic identical to the 1331us baseline: h = E[c]+zs[b] (one f32 add),
// one f32 acc per (row,col), fmaf strictly ascending d, bias added after.
__global__ __launch_bounds__(256, 1)
void k_gemm(const float* __restrict__ E, const float* __restrict__ zs,
            const float* __restrict__ Wv, const float* __restrict__ bv,
            const int* __restrict__ chain, float* __restrict__ Lg,
            int step, int N, int Mshift) {
  __shared__ __align__(16) float xs[RPB * DD];   // 4 KB (h rows, broadcast-read)
  __shared__ int cs[RPB];

  const int t = threadIdx.x;
  const int tile = blockIdx.x % NVT;          // tile == XCD (stable mapping)
  const int n0 = (blockIdx.x / NVT) * RPB;    // N is a multiple of RPB
  const int v0 = tile * VT;

  const int v4 = v0 + (t << 2);               // packed group; max 8960+1020+3 = 9983 < VV: always in-bounds
  const int v1 = v0 + 1024 + t;               // extra column
  const int v1ok = (v1 < VV);                 // only tile 7, t>=19 is OOB
  const int v1c = v1ok ? v1 : (VV - 1);

  if (t < RPB) {
    int n = n0 + t;
    int c = chain[n * TT + step];
    if ((unsigned)c >= VV) c = 0;    // defensive
    cs[t] = c;
  }
  __syncthreads();

  // stage xs rows: h = E[c] + zs[b]  (single f32 add, np order)
  for (int e = t; e < RPB * DD; e += 256) {
    int r = e >> 8, d = e & 255;
    int n = n0 + r;
    int b = n >> Mshift;
    xs[e] = E[cs[r] * DD + d] + zs[b * DD + d];
  }
  __syncthreads();

  const float* w4p = Wv + v4;
  const float* w1p = Wv + v1c;

  float acc4[RPB][4];
  float acc1[RPB];
#pragma unroll
  for (int r = 0; r < RPB; ++r) {
    acc1[r] = 0.f;
#pragma unroll
    for (int j = 0; j < 4; ++j) acc4[r][j] = 0.f;
  }

  // 8-d groups, double-buffered (A/B): W from global, h from LDS
  f32x4u w4A[8], w4B[8];
  float  w1A[8], w1B[8];
  f32x4  h0A[RPB], h1A[RPB], h0B[RPB], h1B[RPB];

#pragma unroll
  for (int u = 0; u < 8; ++u) {
    w4A[u] = *(const f32x4u*)(w4p + (size_t)u * VV);
    w1A[u] = w1p[(size_t)u * VV];
  }
#pragma unroll
  for (int r = 0; r < RPB; ++r) {
    h0A[r] = *(const f32x4*)(xs + r * DD);
    h1A[r] = *(const f32x4*)(xs + r * DD + 4);
  }

  for (int d0 = 0; d0 < DD; d0 += 16) {
    const int dB = d0 + 8;
    // prefetch group B (dB) while computing A
#pragma unroll
    for (int u = 0; u < 8; ++u) {
      w4B[u] = *(const f32x4u*)(w4p + (size_t)(dB + u) * VV);
      w1B[u] = w1p[(size_t)(dB + u) * VV];
    }
#pragma unroll
    for (int r = 0; r < RPB; ++r) {
      h0B[r] = *(const f32x4*)(xs + r * DD + dB);
      h1B[r] = *(const f32x4*)(xs + r * DD + dB + 4);
    }

#pragma unroll
    for (int u = 0; u < 8; ++u) {          // d ascending within group
#pragma unroll
      for (int r = 0; r < RPB; ++r) {
        const float hv = (u < 4) ? h0A[r][u] : h1A[r][u - 4];
#pragma unroll
        for (int j = 0; j < 4; ++j) acc4[r][j] = fmaf(hv, w4A[u][j], acc4[r][j]);
        acc1[r] = fmaf(hv, w1A[u], acc1[r]);
      }
    }

    const int dA = (d0 + 16 < DD) ? (d0 + 16) : 0;   // dummy reload last iter
#pragma unroll
    for (int u = 0; u < 8; ++u) {
      w4A[u] = *(const f32x4u*)(w4p + (size_t)(dA + u) * VV);
      w1A[u] = w1p[(size_t)(dA + u) * VV];
    }
#pragma unroll
    for (int r = 0; r < RPB; ++r) {
      h0A[r] = *(const f32x4*)(xs + r * DD + dA);
      h1A[r] = *(const f32x4*)(xs + r * DD + dA + 4);
    }

#pragma unroll
    for (int u = 0; u < 8; ++u) {
#pragma unroll
      for (int r = 0; r < RPB; ++r) {
        const float hv = (u < 4) ? h0B[r][u] : h1B[r][u - 4];
#pragma unroll
        for (int j = 0; j < 4; ++j) acc4[r][j] = fmaf(hv, w4B[u][j], acc4[r][j]);
        acc1[r] = fmaf(hv, w1B[u], acc1[r]);
      }
    }
  }

  // epilogue: bias after gemm (np), vectorized store for the packed group
  const f32x4u bv4 = *(const f32x4u*)(bv + v4);
#pragma unroll
  for (int r = 0; r < RPB; ++r) {
    f32x4 o;
#pragma unroll
    for (int j = 0; j < 4; ++j) o[j] = acc4[r][j] + bv4[j];
    *(f32x4*)(Lg + (size_t)(n0 + r) * VP + v4) = o;   // 16B aligned: VP%4==0, v4%4==0
  }
  if (v1ok) {
    const float bvv = bv[v1];
#pragma unroll
    for (int r = 0; r < RPB; ++r)
      Lg[(size_t)(n0 + r) * VP + v1] = acc1[r] + bvv;
  }
}

// ---------- kernel 2: np-exact max/top4/pairwise-lse, 1024-thread ----------
// Same math as the passing version: max/top4 under a strict total order are
// partition-independent; row[] contents, leaf segments, pairwise tree and
// double exp/log are bit-identical. Scan now uses dwordx4 loads and the
// branch-free L4 (no scratch).
__global__ __launch_bounds__(1024)
void k_red(const float* __restrict__ Lg, float* __restrict__ topP,
           int* __restrict__ topI) {
  __shared__ __align__(16) float row[VV];   // exp'd values (pairwise sums)
  __shared__ int   segBase[255];
  __shared__ int   segN[255];
  __shared__ float val[255];
  __shared__ float wmax[16];
  __shared__ float wv4[16 * 4];
  __shared__ int   wi4[16 * 4];
  __shared__ float gmS;
  __shared__ float gtv[4];
  __shared__ int   gti[4];

  const int n = blockIdx.x;
  const int t = threadIdx.x;
  const int lane = t & 63;
  const int wid = t >> 6;
  const float* grow = Lg + (size_t)n * VP;

  // ---- load: 3 x4 groups per thread (4t, 4096+4t, 8192+4t) ----
  const int va = t << 2;            // 0..4095, always valid
  const int vb = 4096 + (t << 2);   // 4096..8191, always valid
  const int vc = 8192 + (t << 2);   // valid fully for t<=451; partial t=452
  f32x4 xa = *(const f32x4*)(grow + va);
  f32x4 xb = *(const f32x4*)(grow + vb);
  f32x4 xc;
  const bool cfull = (vc + 3 < VV);
  if (cfull) {
    xc = *(const f32x4*)(grow + vc);
  } else {
#pragma unroll
    for (int j = 0; j < 4; ++j) xc[j] = (vc + j < VV) ? grow[vc + j] : FNEG;
  }

  // ---- scan: max + top4 (branch-free inserts, guarded for OOB) ----
  float m = FNEG;
  L4 top; l4_init(top);
#pragma unroll
  for (int j = 0; j < 4; ++j) { float x = xa[j]; if (x > m) m = x; l4_insert(top, x, va + j); }
#pragma unroll
  for (int j = 0; j < 4; ++j) { float x = xb[j]; if (x > m) m = x; l4_insert(top, x, vb + j); }
#pragma unroll
  for (int j = 0; j < 4; ++j) {
    if (vc + j < VV) { float x = xc[j]; if (x > m) m = x; l4_insert(top, x, vc + j); }
  }

  // intra-wave reduce (64 lanes, butterfly)
  for (int off = 32; off; off >>= 1) {
    float m2 = __shfl_xor(m, off);
    if (m2 > m) m = m2;
    L4 o = l4_shfl_xor(top, off);
    l4_merge(top, o);
  }
  if (lane == 0) {
    wmax[wid] = m;
    wv4[wid * 4 + 0] = top.v0; wi4[wid * 4 + 0] = top.i0;
    wv4[wid * 4 + 1] = top.v1; wi4[wid * 4 + 1] = top.i1;
    wv4[wid * 4 + 2] = top.v2; wi4[wid * 4 + 2] = top.i2;
    wv4[wid * 4 + 3] = top.v3; wi4[wid * 4 + 3] = top.i3;
  }
  if (t == 0) { segBase[0] = 0; segN[0] = VV; }
  __syncthreads();

  // cross-wave merge of the 16 partials (lanes 0..15 of wave 0)
  if (t < 16) {
    float mm = wmax[t];
    L4 a;
    a.v0 = wv4[t * 4 + 0]; a.i0 = wi4[t * 4 + 0];
    a.v1 = wv4[t * 4 + 1]; a.i1 = wi4[t * 4 + 1];
    a.v2 = wv4[t * 4 + 2]; a.i2 = wi4[t * 4 + 2];
    a.v3 = wv4[t * 4 + 3]; a.i3 = wi4[t * 4 + 3];
    for (int off = 1; off < 16; off <<= 1) {
      float m2 = __shfl_xor(mm, off);
      if (m2 > mm) mm = m2;
      L4 o = l4_shfl_xor(a, off);
      l4_merge(a, o);
    }
    if (t == 0) {
      gmS = mm;
      gtv[0] = a.v0; gti[0] = a.i0;
      gtv[1] = a.v1; gti[1] = a.i1;
      gtv[2] = a.v2; gti[2] = a.i2;
      gtv[3] = a.v3; gti[3] = a.i3;
    }
  }

  // numpy pairwise segment tree (structure unchanged)
  for (int L = 0; L < 7; ++L) {
    int first = (1 << L) - 1, cnt = 1 << L;
    if (t < cnt) {
      int p = first + t;
      int np_ = segN[p], bp = segBase[p];
      int n2 = np_ / 2; n2 -= n2 % 8;
      segBase[2 * p + 1] = bp;       segN[2 * p + 1] = n2;
      segBase[2 * p + 2] = bp + n2;  segN[2 * p + 2] = np_ - n2;
    }
    __syncthreads();
  }
  const float gm = gmS;   // visible: t==0 wrote it before the tree barriers

  // exp pass: f32 sub, double exp, store f32 (identical values per v)
  {
    f32x4 ea, eb;
#pragma unroll
    for (int j = 0; j < 4; ++j) ea[j] = (float)exp((double)(xa[j] - gm));
#pragma unroll
    for (int j = 0; j < 4; ++j) eb[j] = (float)exp((double)(xb[j] - gm));
    *(f32x4*)(row + va) = ea;      // ds_write_b128, 16B aligned
    *(f32x4*)(row + vb) = eb;
    if (cfull) {
      f32x4 ec;
#pragma unroll
      for (int j = 0; j < 4; ++j) ec[j] = (float)exp((double)(xc[j] - gm));
      *(f32x4*)(row + vc) = ec;
    } else {
#pragma unroll
      for (int j = 0; j < 4; ++j)
        if (vc + j < VV) row[vc + j] = (float)exp((double)(xc[j] - gm));
    }
  }
  __syncthreads();

  if (t < 128) {
    int nd = 127 + t;
    val[nd] = np_block_sum(&row[segBase[nd]], segN[nd]);
  }
  for (int L = 6; L >= 0; --L) {
    __syncthreads();
    int first = (1 << L) - 1, cnt = 1 << L;
    if (t < cnt) {
      int p = first + t;
      val[p] = val[2 * p + 1] + val[2 * p + 2];
    }
  }

  if (t == 0) {
    float ls = (float)log((double)val[0]);
#pragma unroll
    for (int j = 0; j < 4; ++j) {
      topP[n * 4 + j] = (gtv[j] - gm) - ls;   // (x - m) - log(s), two f32 subs
      topI[n * 4 + j] = gti[j];
    }
  }
}

// ---------- kernel 3: beam update, wave-parallel (UNCHANGED) ----------
__global__ __launch_bounds__(512)
void k_beam(const float* __restrict__ topP, const int* __restrict__ topI,
            float* __restrict__ prob, const int* __restrict__ chain_cur,
            int* __restrict__ chain_next, int step) {
  __shared__ int sel_src[BB][8];
  __shared__ int sel_tok[BB][8];

  const int tid = threadIdx.x;
  const int b = tid >> 5;      // batch 0..15
  const int c = tid & 31;      // candidate 0..31

  if (step == 0) {
    for (int e = tid; e < BB * KK * TT; e += 512) {
      int dst = e >> 4, q = e & 15;
      int bb = dst >> 2, kk = dst & 3;
      int val;
      if (q == 1) {
        int tok = topI[bb * 4 + kk]; if ((unsigned)tok >= VV) tok = 0;
        val = tok;
      } else {
        val = chain_cur[bb * TT + q];
      }
      chain_next[dst * TT + q] = val;
    }
    if (tid < BB * KK) {
      int bb = tid >> 2, kk = tid & 3;
      prob[bb * 8 + kk] = topP[bb * 4 + kk];
    }
    return;
  }

  const int M = (step == 1) ? 4 : 8;
  const int nc = M * 4;

  float act;
  if (c < nc) {
    int m = c >> 2, k = c & 3;
    act = prob[b * 8 + m] * topP[(b * M + m) * 4 + k];
  } else {
    act = -INFINITY;
  }

  for (int j = 0; j < 8; ++j) {
    float rv = act; int ri = c;
#pragma unroll
    for (int off = 1; off < 32; off <<= 1) {
      float v2 = __shfl_xor(rv, off, 32);
      int   i2 = __shfl_xor(ri, off, 32);
      if (v2 > rv || (v2 == rv && i2 < ri)) { rv = v2; ri = i2; }
    }
    if (c == ri) act = -INFINITY;          // mark used
    if (c == 0) {
      int m = ri >> 2, k = ri & 3;
      int src = b * M + m;
      int tok = topI[src * 4 + k]; if ((unsigned)tok >= VV) tok = 0;
      sel_src[b][j] = src;
      sel_tok[b][j] = tok;
      prob[b * 8 + j] = rv;
    }
  }
  __syncthreads();

  for (int e = tid; e < BB * 8 * TT; e += 512) {
    int dst = e >> 4, q = e & 15;
    int bb = dst >> 3, j = dst & 7;
    int src = sel_src[bb][j];
    int val = (q == step + 1) ? sel_tok[bb][j] : chain_cur[src * TT + q];
    chain_next[dst * TT + q] = val;
  }
}

// ---------- kernel 4: finalize: loc_chain + tim_chain (UNCHANGED) ----------
__global__ __launch_bounds__(64)
void k_final(const int* __restrict__ chain, const float* __restrict__ E,
             const float* __restrict__ Wc, const float* __restrict__ bc,
             const float* __restrict__ Wt, const float* __restrict__ zt,
             const float* __restrict__ Wzt, float* __restrict__ out) {
  int blk = blockIdx.x;           // 224 = B*(T-2)
  int b = blk / (TT - 2), t = blk % (TT - 2);
  int lane = threadIdx.x;         // 64 = C
  int loc = chain[(b * 8) * TT + 1 + t];   // best beam, positions 1..T-2
  if ((unsigned)loc >= VV) loc = 0;        // defensive
  double acc = (double)bc[lane];
  const float* er = E + loc * DD;
  for (int d = 0; d < DD; ++d) acc += (double)er[d] * (double)Wc[d * CC + lane];
  double val = tanh(acc) * (double)Wt[lane];
  const float* ztr = zt + b * DD;
#pragma unroll
  for (int q = 0; q < 4; ++q) val += (double)ztr[lane * 4 + q] * (double)Wzt[lane * 4 + q];
  for (int off = 32; off; off >>= 1) val += __shfl_down(val, off);
  if (lane == 0) {
    out[b * (TT - 2) + t] = (float)loc;                 // loc_chain as float
    out[BB * (TT - 2) + b * (TT - 2) + t] = (float)val; // tim_chain
  }
}

// ---------- host ----------
extern "C" void kernel_launch(void* const* d_in, const int* in_sizes, int n_in,
                              void* d_out, int out_size, void* d_ws, size_t ws_size,
                              hipStream_t stream) {
  const int*   loc_tar = (const int*)  d_in[0];
  const float* zs      = (const float*)d_in[1];
  const float* zt      = (const float*)d_in[2];
  const float* E       = (const float*)d_in[3];
  const float* Wv      = (const float*)d_in[4];
  const float* bv      = (const float*)d_in[5];
  const float* Wc      = (const float*)d_in[6];
  const float* bc      = (const float*)d_in[7];
  const float* Wt      = (const float*)d_in[8];
  const float* Wzt     = (const float*)d_in[9];
  float* out = (float*)d_out;

  char* w = (char*)d_ws;
  float* Lg     = (float*)(w);                   // 128*10016*4 = 5,128,192 B
  float* topP   = (float*)(w + 5128192);         // 512 f32 = 2048 B
  int*   topI   = (int*)  (w + 5130240);         // 512 int = 2048 B
  float* prob   = (float*)(w + 5132288);         // 128 f32 = 512 B
  int*   chainA = (int*)  (w + 5132800);         // 2048 int = 8192 B
  int*   chainB = (int*)  (w + 5140992);         // 2048 int = 8192 B

  k_init<<<1, 256, 0, stream>>>(loc_tar, chainA);

  int N = BB;
  int* cur = chainA;
  int* nxt = chainB;
  for (int i = 0; i < TT - 1; ++i) {
    int Mshift = (i == 0) ? 0 : ((i == 1) ? 2 : 3);
    int nrg = N / RPB;
    k_gemm<<<nrg * NVT, 256, 0, stream>>>(E, zs, Wv, bv, cur, Lg, i, N, Mshift);
    k_red<<<N, 1024, 0, stream>>>(Lg, topP, topI);
    k_beam<<<1, 512, 0, stream>>>(topP, topI, prob, cur, nxt, i);
    int* t2 = cur; cur = nxt; nxt = t2;
    N = (i == 0) ? BB * KK : BB * 2 * KK;
  }

  k_final<<<BB * (TT - 2), 64, 0, stream>>>(cur, E, Wc, bc, Wt, zt, Wzt, out);
}